// Round 1
// baseline (5883.525 us; speedup 1.0000x reference)
//
#include <hip/hip_runtime.h>
#include <cstdint>
#include <cstddef>

#define D 128
#define TILE_ROWS 64
#define NSCALE 1.8f
#define NEPS 1e-12f

// ---------------- utility kernels ----------------

__global__ __launch_bounds__(256) void zero_kernel(float* __restrict__ p, int n4) {
    int i = blockIdx.x * blockDim.x + threadIdx.x;
    if (i < n4) ((float4*)p)[i] = make_float4(0.f, 0.f, 0.f, 0.f);
}

__global__ __launch_bounds__(256) void deg_kernel(const int* __restrict__ src,
                                                  const int* __restrict__ dst,
                                                  float* __restrict__ deg_out,
                                                  float* __restrict__ deg_in, int ne) {
    int e = blockIdx.x * blockDim.x + threadIdx.x;
    if (e < ne) {
        atomicAdd(deg_out + src[e], 1.0f);
        atomicAdd(deg_in + dst[e], 1.0f);
    }
}

__global__ __launch_bounds__(256) void norm_kernel(float* __restrict__ deg, int n) {
    int i = blockIdx.x * blockDim.x + threadIdx.x;
    if (i < n) deg[i] = rsqrtf(fmaxf(deg[i], 1.0f));
}

// out[row] *= nrm[row], vectorized float4 (32 float4 per row)
__global__ __launch_bounds__(256) void scale_rows_kernel(float* __restrict__ h,
                                                         const float* __restrict__ nrm, int n4) {
    int i = blockIdx.x * blockDim.x + threadIdx.x;
    if (i < n4) {
        int row = i >> 5;
        float s = nrm[row];
        float4 v = ((float4*)h)[i];
        v.x *= s; v.y *= s; v.z *= s; v.w *= s;
        ((float4*)h)[i] = v;
    }
}

// ---------------- fused linear + L2-rownorm*1.8 + norm_out scale ----------------
// out[n][k] = (sum_d pre[n]*x[n][d] * W[k][d] + b[k]) , row-L2-normalized *1.8, * post[n]
// Tile: 64 rows x 128 cols per block; 256 threads; thread = 8 rows x 4 cols.
// LDS: W chunk transposed [32 k][128 c] (pad 132) + x tile [64][128]  = 48.5 KB
__global__ __launch_bounds__(256) void mlp_kernel(const float* __restrict__ x,
                                                  const float* __restrict__ W,
                                                  const float* __restrict__ b,
                                                  const float* __restrict__ pre,   // may be null
                                                  const float* __restrict__ post,  // norm_out
                                                  float* __restrict__ out, int N) {
    __shared__ float Wt[32 * 132];        // Wt[kl][c] = W[c][ph*32+kl]
    __shared__ float xs[TILE_ROWS * 128];

    const int t = threadIdx.x;
    const int tc = t & 31;    // col group: cols 4*tc..4*tc+3
    const int tr = t >> 5;    // row group: rows 8*tr..8*tr+7
    const int row0 = blockIdx.x * TILE_ROWS;

    // stage x tile (optionally pre-scaled by norm_in)
    #pragma unroll
    for (int i = 0; i < 8; ++i) {
        int idx4 = t + 256 * i;            // [0, 2048)
        int r = idx4 >> 5;
        int c4 = (idx4 & 31) * 4;
        int row = row0 + r;
        float4 v = make_float4(0.f, 0.f, 0.f, 0.f);
        if (row < N) {
            v = *(const float4*)(x + (size_t)row * D + c4);
            if (pre) {
                float s = pre[row];
                v.x *= s; v.y *= s; v.z *= s; v.w *= s;
            }
        }
        *(float4*)(xs + r * 128 + c4) = v;
    }

    float4 acc[8];
    #pragma unroll
    for (int i = 0; i < 8; ++i) acc[i] = make_float4(0.f, 0.f, 0.f, 0.f);

    for (int ph = 0; ph < 4; ++ph) {
        __syncthreads();
        // load+transpose W chunk: k in [ph*32, ph*32+32)
        #pragma unroll
        for (int i = 0; i < 4; ++i) {
            int idx4 = t + 256 * i;        // [0, 1024)
            int c = idx4 >> 3;             // output col (W row)
            int kl0 = (idx4 & 7) * 4;      // local k
            float4 v = *(const float4*)(W + (size_t)c * D + ph * 32 + kl0);
            Wt[(kl0 + 0) * 132 + c] = v.x;
            Wt[(kl0 + 1) * 132 + c] = v.y;
            Wt[(kl0 + 2) * 132 + c] = v.z;
            Wt[(kl0 + 3) * 132 + c] = v.w;
        }
        __syncthreads();

        #pragma unroll
        for (int kk4 = 0; kk4 < 8; ++kk4) {
            float4 wv0 = *(const float4*)(Wt + (4 * kk4 + 0) * 132 + 4 * tc);
            float4 wv1 = *(const float4*)(Wt + (4 * kk4 + 1) * 132 + 4 * tc);
            float4 wv2 = *(const float4*)(Wt + (4 * kk4 + 2) * 132 + 4 * tc);
            float4 wv3 = *(const float4*)(Wt + (4 * kk4 + 3) * 132 + 4 * tc);
            #pragma unroll
            for (int i = 0; i < 8; ++i) {
                float4 a = *(const float4*)(xs + (8 * tr + i) * 128 + ph * 32 + 4 * kk4);
                acc[i].x += a.x * wv0.x + a.y * wv1.x + a.z * wv2.x + a.w * wv3.x;
                acc[i].y += a.x * wv0.y + a.y * wv1.y + a.z * wv2.y + a.w * wv3.y;
                acc[i].z += a.x * wv0.z + a.y * wv1.z + a.z * wv2.z + a.w * wv3.z;
                acc[i].w += a.x * wv0.w + a.y * wv1.w + a.z * wv2.w + a.w * wv3.w;
            }
        }
    }

    // epilogue: bias, row L2 norm (butterfly over the 32 tc lanes), scale, store
    float4 bv = *(const float4*)(b + 4 * tc);
    float ssv[8];
    #pragma unroll
    for (int i = 0; i < 8; ++i) {
        acc[i].x += bv.x; acc[i].y += bv.y; acc[i].z += bv.z; acc[i].w += bv.w;
        ssv[i] = acc[i].x * acc[i].x + acc[i].y * acc[i].y +
                 acc[i].z * acc[i].z + acc[i].w * acc[i].w;
    }
    #pragma unroll
    for (int m = 16; m >= 1; m >>= 1) {
        #pragma unroll
        for (int i = 0; i < 8; ++i) ssv[i] += __shfl_xor(ssv[i], m);
    }
    #pragma unroll
    for (int i = 0; i < 8; ++i) {
        int row = row0 + 8 * tr + i;
        if (row < N) {
            float f = NSCALE / fmaxf(sqrtf(ssv[i]), NEPS) * post[row];
            float4 y;
            y.x = acc[i].x * f; y.y = acc[i].y * f; y.z = acc[i].z * f; y.w = acc[i].w * f;
            *(float4*)(out + (size_t)row * D + 4 * tc) = y;
        }
    }
}

// ---------------- edge scatter: agg[dst] += h[src] ----------------
// 32 lanes per edge, float4 per lane, 4 atomicAdds
__global__ __launch_bounds__(256) void scatter_kernel(const float* __restrict__ h,
                                                      const int* __restrict__ src,
                                                      const int* __restrict__ dst,
                                                      float* __restrict__ agg, int ne) {
    int lane = threadIdx.x & 31;
    int e = (blockIdx.x * blockDim.x + threadIdx.x) >> 5;
    if (e < ne) {
        int s = src[e];
        int d = dst[e];
        float4 v = *(const float4*)(h + (size_t)s * D + lane * 4);
        float* p = agg + (size_t)d * D + lane * 4;
        atomicAdd(p + 0, v.x);
        atomicAdd(p + 1, v.y);
        atomicAdd(p + 2, v.z);
        atomicAdd(p + 3, v.w);
    }
}

// ---------------- launch ----------------

extern "C" void kernel_launch(void* const* d_in, const int* in_sizes, int n_in,
                              void* d_out, int out_size, void* d_ws, size_t ws_size,
                              hipStream_t stream) {
    const float* x  = (const float*)d_in[0];
    const float* W1 = (const float*)d_in[1];
    const float* b1 = (const float*)d_in[2];
    const float* W2 = (const float*)d_in[3];
    const float* b2 = (const float*)d_in[4];
    const int* src  = (const int*)d_in[5];
    const int* dst  = (const int*)d_in[6];
    float* out = (float*)d_out;

    const int N  = in_sizes[0] / D;   // 100000
    const int NE = in_sizes[5];       // 1600000

    float* deg_out = (float*)d_ws;          // becomes norm_out
    float* deg_in  = deg_out + N;           // becomes norm_in
    float* A = (float*)((char*)d_ws + (1 << 20));  // 51.2 MB h buffer

    const int n4_h = N * (D / 4);           // float4 count of a [N,128] buffer
    const int n4_deg = (2 * N + 3) / 4;

    // degrees -> norms
    zero_kernel<<<(n4_deg + 255) / 256, 256, 0, stream>>>(deg_out, n4_deg);
    deg_kernel<<<(NE + 255) / 256, 256, 0, stream>>>(src, dst, deg_out, deg_in, NE);
    norm_kernel<<<(2 * N + 255) / 256, 256, 0, stream>>>(deg_out, 2 * N);

    const int mlp_blocks = (N + TILE_ROWS - 1) / TILE_ROWS;
    const int sc_blocks = (NE * 32 + 255) / 256;  // 32 lanes per edge

    // layer 1: mlp(x) -> A ; agg -> out ; (norm_in folded into layer2 load)
    mlp_kernel<<<mlp_blocks, 256, 0, stream>>>(x, W1, b1, nullptr, deg_out, A, N);
    zero_kernel<<<(n4_h + 255) / 256, 256, 0, stream>>>(out, n4_h);
    scatter_kernel<<<sc_blocks, 256, 0, stream>>>(A, src, dst, out, NE);

    // layer 2: mlp(norm_in * h1) -> A ; agg -> out ; final norm_in scale
    mlp_kernel<<<mlp_blocks, 256, 0, stream>>>(out, W2, b2, deg_in, deg_out, A, N);
    zero_kernel<<<(n4_h + 255) / 256, 256, 0, stream>>>(out, n4_h);
    scatter_kernel<<<sc_blocks, 256, 0, stream>>>(A, src, dst, out, NE);
    scale_rows_kernel<<<(n4_h + 255) / 256, 256, 0, stream>>>(out, deg_in, n4_h);
}

// Round 2
// 830.643 us; speedup vs baseline: 7.0831x; 7.0831x over previous
//
#include <hip/hip_runtime.h>
#include <cstdint>
#include <cstddef>

#define D 128
#define TILE_ROWS 64
#define NSCALE 1.8f
#define NEPS 1e-12f

// ---------------- utility kernels ----------------

__global__ __launch_bounds__(256) void zero_kernel(float* __restrict__ p, int n4) {
    int i = blockIdx.x * blockDim.x + threadIdx.x;
    if (i < n4) ((float4*)p)[i] = make_float4(0.f, 0.f, 0.f, 0.f);
}

// int histograms of src and dst
__global__ __launch_bounds__(256) void hist_kernel(const int* __restrict__ src,
                                                   const int* __restrict__ dst,
                                                   int* __restrict__ cnt_src,
                                                   int* __restrict__ cnt_dst, int ne) {
    int e = blockIdx.x * blockDim.x + threadIdx.x;
    if (e < ne) {
        atomicAdd(cnt_src + src[e], 1);
        atomicAdd(cnt_dst + dst[e], 1);
    }
}

__global__ __launch_bounds__(256) void norm_kernel(const int* __restrict__ cnt_src,
                                                   const int* __restrict__ cnt_dst,
                                                   float* __restrict__ norm_out,
                                                   float* __restrict__ norm_in, int n) {
    int i = blockIdx.x * blockDim.x + threadIdx.x;
    if (i < n) {
        norm_out[i] = rsqrtf((float)max(cnt_src[i], 1));
        norm_in[i]  = rsqrtf((float)max(cnt_dst[i], 1));
    }
}

// ---------------- exclusive scan (3-phase) ----------------

__global__ __launch_bounds__(256) void scan1_kernel(const int* __restrict__ cnt,
                                                    int* __restrict__ excl,
                                                    int* __restrict__ bsum, int n) {
    __shared__ int s[256];
    int i = blockIdx.x * 256 + threadIdx.x;
    int v = (i < n) ? cnt[i] : 0;
    s[threadIdx.x] = v;
    __syncthreads();
    #pragma unroll
    for (int off = 1; off < 256; off <<= 1) {
        int t = (threadIdx.x >= off) ? s[threadIdx.x - off] : 0;
        __syncthreads();
        s[threadIdx.x] += t;
        __syncthreads();
    }
    if (i < n) excl[i] = s[threadIdx.x] - v;
    if (threadIdx.x == 255) bsum[blockIdx.x] = s[255];
}

__global__ void scan2_kernel(int* __restrict__ bsum, int nb) {
    if (threadIdx.x == 0 && blockIdx.x == 0) {
        int run = 0;
        for (int i = 0; i < nb; ++i) { int v = bsum[i]; bsum[i] = run; run += v; }
    }
}

__global__ __launch_bounds__(256) void scan3_kernel(int* __restrict__ excl,
                                                    const int* __restrict__ bsum, int n) {
    int i = blockIdx.x * 256 + threadIdx.x;
    if (i < n) excl[i] += bsum[blockIdx.x];
}

// ---------------- bucket edges into CSR order by dst ----------------

__global__ __launch_bounds__(256) void bucket_kernel(const int* __restrict__ src,
                                                     const int* __restrict__ dst,
                                                     const int* __restrict__ offs,
                                                     int* __restrict__ cursor,
                                                     int* __restrict__ sorted_src, int ne) {
    int e = blockIdx.x * blockDim.x + threadIdx.x;
    if (e < ne) {
        int d = dst[e];
        int pos = offs[d] + atomicAdd(cursor + d, 1);
        sorted_src[pos] = src[e];
    }
}

// ---------------- fused linear + L2-rownorm*1.8 + norm_out scale ----------------
// Tile: 64 rows x 128 cols per block; 256 threads; thread = 8 rows x 4 cols.
__global__ __launch_bounds__(256) void mlp_kernel(const float* __restrict__ x,
                                                  const float* __restrict__ W,
                                                  const float* __restrict__ b,
                                                  const float* __restrict__ post,  // norm_out
                                                  float* __restrict__ out, int N) {
    __shared__ float Wt[32 * 132];        // Wt[kl][c] = W[c][ph*32+kl]
    __shared__ float xs[TILE_ROWS * 128];

    const int t = threadIdx.x;
    const int tc = t & 31;    // col group: cols 4*tc..4*tc+3
    const int tr = t >> 5;    // row group: rows 8*tr..8*tr+7
    const int row0 = blockIdx.x * TILE_ROWS;

    #pragma unroll
    for (int i = 0; i < 8; ++i) {
        int idx4 = t + 256 * i;            // [0, 2048)
        int r = idx4 >> 5;
        int c4 = (idx4 & 31) * 4;
        int row = row0 + r;
        float4 v = make_float4(0.f, 0.f, 0.f, 0.f);
        if (row < N) v = *(const float4*)(x + (size_t)row * D + c4);
        *(float4*)(xs + r * 128 + c4) = v;
    }

    float4 acc[8];
    #pragma unroll
    for (int i = 0; i < 8; ++i) acc[i] = make_float4(0.f, 0.f, 0.f, 0.f);

    for (int ph = 0; ph < 4; ++ph) {
        __syncthreads();
        #pragma unroll
        for (int i = 0; i < 4; ++i) {
            int idx4 = t + 256 * i;        // [0, 1024)
            int c = idx4 >> 3;             // output col (W row)
            int kl0 = (idx4 & 7) * 4;      // local k
            float4 v = *(const float4*)(W + (size_t)c * D + ph * 32 + kl0);
            Wt[(kl0 + 0) * 132 + c] = v.x;
            Wt[(kl0 + 1) * 132 + c] = v.y;
            Wt[(kl0 + 2) * 132 + c] = v.z;
            Wt[(kl0 + 3) * 132 + c] = v.w;
        }
        __syncthreads();

        #pragma unroll
        for (int kk4 = 0; kk4 < 8; ++kk4) {
            float4 wv0 = *(const float4*)(Wt + (4 * kk4 + 0) * 132 + 4 * tc);
            float4 wv1 = *(const float4*)(Wt + (4 * kk4 + 1) * 132 + 4 * tc);
            float4 wv2 = *(const float4*)(Wt + (4 * kk4 + 2) * 132 + 4 * tc);
            float4 wv3 = *(const float4*)(Wt + (4 * kk4 + 3) * 132 + 4 * tc);
            #pragma unroll
            for (int i = 0; i < 8; ++i) {
                float4 a = *(const float4*)(xs + (8 * tr + i) * 128 + ph * 32 + 4 * kk4);
                acc[i].x += a.x * wv0.x + a.y * wv1.x + a.z * wv2.x + a.w * wv3.x;
                acc[i].y += a.x * wv0.y + a.y * wv1.y + a.z * wv2.y + a.w * wv3.y;
                acc[i].z += a.x * wv0.z + a.y * wv1.z + a.z * wv2.z + a.w * wv3.z;
                acc[i].w += a.x * wv0.w + a.y * wv1.w + a.z * wv2.w + a.w * wv3.w;
            }
        }
    }

    float4 bv = *(const float4*)(b + 4 * tc);
    float ssv[8];
    #pragma unroll
    for (int i = 0; i < 8; ++i) {
        acc[i].x += bv.x; acc[i].y += bv.y; acc[i].z += bv.z; acc[i].w += bv.w;
        ssv[i] = acc[i].x * acc[i].x + acc[i].y * acc[i].y +
                 acc[i].z * acc[i].z + acc[i].w * acc[i].w;
    }
    #pragma unroll
    for (int m = 16; m >= 1; m >>= 1) {
        #pragma unroll
        for (int i = 0; i < 8; ++i) ssv[i] += __shfl_xor(ssv[i], m);
    }
    #pragma unroll
    for (int i = 0; i < 8; ++i) {
        int row = row0 + 8 * tr + i;
        if (row < N) {
            float f = NSCALE / fmaxf(sqrtf(ssv[i]), NEPS) * post[row];
            float4 y;
            y.x = acc[i].x * f; y.y = acc[i].y * f; y.z = acc[i].z * f; y.w = acc[i].w * f;
            *(float4*)(out + (size_t)row * D + 4 * tc) = y;
        }
    }
}

// ---------------- CSR gather-aggregate: out[n] = norm_in[n] * sum_{e in row n} A[src[e]] ----
// 32 lanes per dst node, float4 per lane, accumulate in registers, single write.
__global__ __launch_bounds__(256) void agg_kernel(const float* __restrict__ A,
                                                  const int* __restrict__ sorted_src,
                                                  const int* __restrict__ offs,
                                                  const int* __restrict__ cnt,
                                                  const float* __restrict__ norm_in,
                                                  float* __restrict__ out, int N) {
    int g = (blockIdx.x * blockDim.x + threadIdx.x) >> 5;  // node
    int lane = threadIdx.x & 31;
    if (g >= N) return;
    int beg = offs[g];
    int len = cnt[g];
    float4 acc = make_float4(0.f, 0.f, 0.f, 0.f);
    for (int i = 0; i < len; ++i) {
        int s = sorted_src[beg + i];
        float4 v = *(const float4*)(A + (size_t)s * D + lane * 4);
        acc.x += v.x; acc.y += v.y; acc.z += v.z; acc.w += v.w;
    }
    float sc = norm_in[g];
    acc.x *= sc; acc.y *= sc; acc.z *= sc; acc.w *= sc;
    *(float4*)(out + (size_t)g * D + lane * 4) = acc;
}

// ---------------- launch ----------------

extern "C" void kernel_launch(void* const* d_in, const int* in_sizes, int n_in,
                              void* d_out, int out_size, void* d_ws, size_t ws_size,
                              hipStream_t stream) {
    const float* x  = (const float*)d_in[0];
    const float* W1 = (const float*)d_in[1];
    const float* b1 = (const float*)d_in[2];
    const float* W2 = (const float*)d_in[3];
    const float* b2 = (const float*)d_in[4];
    const int* src  = (const int*)d_in[5];
    const int* dst  = (const int*)d_in[6];
    float* out = (float*)d_out;

    const int N  = in_sizes[0] / D;   // 100000
    const int NE = in_sizes[5];       // 1600000
    const int NB = (N + 255) / 256;   // scan blocks

    // workspace layout (256B aligned chunks)
    char* w = (char*)d_ws;
    auto take = [&](size_t bytes) { char* p = w; w += (bytes + 255) & ~(size_t)255; return p; };
    int*   cnt_src  = (int*)take((size_t)N * 4);
    int*   cnt_dst  = (int*)take((size_t)N * 4);
    int*   cursor   = (int*)take((size_t)N * 4);
    int*   offs     = (int*)take((size_t)N * 4);
    int*   bsum     = (int*)take((size_t)NB * 4);
    float* norm_out = (float*)take((size_t)N * 4);
    float* norm_in  = (float*)take((size_t)N * 4);
    int*   ssrc     = (int*)take((size_t)NE * 4);
    float* A        = (float*)take((size_t)N * D * 4);

    // zero cnt_src, cnt_dst, cursor (contiguous region)
    size_t zero_bytes = (char*)offs - (char*)cnt_src;
    int zn4 = (int)(zero_bytes / 16);
    zero_kernel<<<(zn4 + 255) / 256, 256, 0, stream>>>((float*)cnt_src, zn4);

    // histograms -> norms
    hist_kernel<<<(NE + 255) / 256, 256, 0, stream>>>(src, dst, cnt_src, cnt_dst, NE);
    norm_kernel<<<(N + 255) / 256, 256, 0, stream>>>(cnt_src, cnt_dst, norm_out, norm_in, N);

    // exclusive scan of cnt_dst -> offs
    scan1_kernel<<<NB, 256, 0, stream>>>(cnt_dst, offs, bsum, N);
    scan2_kernel<<<1, 64, 0, stream>>>(bsum, NB);
    scan3_kernel<<<NB, 256, 0, stream>>>(offs, bsum, N);

    // bucket edges by dst
    bucket_kernel<<<(NE + 255) / 256, 256, 0, stream>>>(src, dst, offs, cursor, ssrc, NE);

    const int mlp_blocks = (N + TILE_ROWS - 1) / TILE_ROWS;
    const int agg_blocks = (N * 32 + 255) / 256;

    // layer 1: mlp(x)->A (norm_out folded); agg(A)->out (norm_in folded)
    mlp_kernel<<<mlp_blocks, 256, 0, stream>>>(x, W1, b1, norm_out, A, N);
    agg_kernel<<<agg_blocks, 256, 0, stream>>>(A, ssrc, offs, cnt_dst, norm_in, out, N);

    // layer 2
    mlp_kernel<<<mlp_blocks, 256, 0, stream>>>(out, W2, b2, norm_out, A, N);
    agg_kernel<<<agg_blocks, 256, 0, stream>>>(A, ssrc, offs, cnt_dst, norm_in, out, N);
}

// Round 3
// 572.082 us; speedup vs baseline: 10.2844x; 1.4520x over previous
//
#include <hip/hip_runtime.h>
#include <cstdint>
#include <cstddef>

#define D 128
#define NSCALE 1.8f
#define NEPS 1e-12f

typedef __attribute__((ext_vector_type(8))) short bf16x8;
typedef __attribute__((ext_vector_type(4))) float f32x4;

__device__ __forceinline__ ushort bf16_rtn(float f) {
    uint32_t u = __float_as_uint(f);
    u = u + 0x7FFFu + ((u >> 16) & 1u);
    return (ushort)(u >> 16);
}

// ---------------- utility kernels ----------------

__global__ __launch_bounds__(256) void zero_kernel(float* __restrict__ p, int n4) {
    int i = blockIdx.x * blockDim.x + threadIdx.x;
    if (i < n4) ((float4*)p)[i] = make_float4(0.f, 0.f, 0.f, 0.f);
}

__global__ __launch_bounds__(256) void hist_kernel(const int* __restrict__ src,
                                                   const int* __restrict__ dst,
                                                   int* __restrict__ cnt_src,
                                                   int* __restrict__ cnt_dst, int ne) {
    int e = blockIdx.x * blockDim.x + threadIdx.x;
    if (e < ne) {
        atomicAdd(cnt_src + src[e], 1);
        atomicAdd(cnt_dst + dst[e], 1);
    }
}

__global__ __launch_bounds__(256) void norm_kernel(const int* __restrict__ cnt_src,
                                                   const int* __restrict__ cnt_dst,
                                                   float* __restrict__ norm_out,
                                                   float* __restrict__ norm_in, int n) {
    int i = blockIdx.x * blockDim.x + threadIdx.x;
    if (i < n) {
        norm_out[i] = rsqrtf((float)max(cnt_src[i], 1));
        norm_in[i]  = rsqrtf((float)max(cnt_dst[i], 1));
    }
}

// ---------------- exclusive scan (3-phase) ----------------

__global__ __launch_bounds__(256) void scan1_kernel(const int* __restrict__ cnt,
                                                    int* __restrict__ excl,
                                                    int* __restrict__ bsum, int n) {
    __shared__ int s[256];
    int i = blockIdx.x * 256 + threadIdx.x;
    int v = (i < n) ? cnt[i] : 0;
    s[threadIdx.x] = v;
    __syncthreads();
    #pragma unroll
    for (int off = 1; off < 256; off <<= 1) {
        int t = (threadIdx.x >= off) ? s[threadIdx.x - off] : 0;
        __syncthreads();
        s[threadIdx.x] += t;
        __syncthreads();
    }
    if (i < n) excl[i] = s[threadIdx.x] - v;
    if (threadIdx.x == 255) bsum[blockIdx.x] = s[255];
}

// block-parallel exclusive scan of bsum (nb <= 512)
__global__ __launch_bounds__(512) void scan2_kernel(int* __restrict__ bsum, int nb) {
    __shared__ int s[512];
    int t = threadIdx.x;
    int v = (t < nb) ? bsum[t] : 0;
    s[t] = v;
    __syncthreads();
    #pragma unroll
    for (int off = 1; off < 512; off <<= 1) {
        int u = (t >= off) ? s[t - off] : 0;
        __syncthreads();
        s[t] += u;
        __syncthreads();
    }
    if (t < nb) bsum[t] = s[t] - v;
}

__global__ __launch_bounds__(256) void scan3_kernel(int* __restrict__ excl,
                                                    const int* __restrict__ bsum, int n) {
    int i = blockIdx.x * 256 + threadIdx.x;
    if (i < n) excl[i] += bsum[blockIdx.x];
}

// ---------------- bucket edges into CSR order by dst ----------------

__global__ __launch_bounds__(256) void bucket_kernel(const int* __restrict__ src,
                                                     const int* __restrict__ dst,
                                                     const int* __restrict__ offs,
                                                     int* __restrict__ cursor,
                                                     int* __restrict__ sorted_src, int ne) {
    int e = blockIdx.x * blockDim.x + threadIdx.x;
    if (e < ne) {
        int d = dst[e];
        int pos = offs[d] + atomicAdd(cursor + d, 1);
        sorted_src[pos] = src[e];
    }
}

// ---------------- MFMA MLP: out = bf16( norm_out * 1.8 * L2rownorm(X@W^T + b) ) ----
// X fp32 [N,128]; split in-registers to bf16 hi+lo (exact). W fp32 [128,128] cast
// RTN-bf16 into LDS in B-fragment order. 256 thr = 4 waves; wave = 32 rows.
__global__ __launch_bounds__(256) void mlp_mfma_kernel(const float* __restrict__ X,
                                                       const float* __restrict__ W,
                                                       const float* __restrict__ b,
                                                       const float* __restrict__ post,
                                                       ushort* __restrict__ Abuf, int N) {
    __shared__ ushort Wf[128 * 128];   // 32 KB, fragment-ordered

    const int t = threadIdx.x;
    const int wave = t >> 6;
    const int lane = t & 63;
    const int q = lane >> 4;           // quad 0..3
    const int l16 = lane & 15;

    // ---- stage W into LDS in B-fragment order, RTN bf16 ----
    #pragma unroll
    for (int it = 0; it < 8; ++it) {
        int f = t + 256 * it;          // 16B chunk id, 0..2047
        int j = f >> 8;                // ntile 0..7
        int p = (f >> 6) & 3;          // kstep 0..3
        int ln = f & 63;
        int n = 16 * j + (ln & 15);
        int k0 = 32 * p + 8 * (ln >> 4);
        const float* srcp = W + n * D + k0;
        float4 a0 = *(const float4*)(srcp);
        float4 a1 = *(const float4*)(srcp + 4);
        bf16x8 v;
        v[0] = (short)bf16_rtn(a0.x); v[1] = (short)bf16_rtn(a0.y);
        v[2] = (short)bf16_rtn(a0.z); v[3] = (short)bf16_rtn(a0.w);
        v[4] = (short)bf16_rtn(a1.x); v[5] = (short)bf16_rtn(a1.y);
        v[6] = (short)bf16_rtn(a1.z); v[7] = (short)bf16_rtn(a1.w);
        ((bf16x8*)Wf)[f] = v;
    }

    // ---- load A fragments: 2 row-tiles (32 rows), split hi/lo ----
    const int r0 = blockIdx.x * 128 + wave * 32;
    bf16x8 ahi[2][4], alo[2][4];
    #pragma unroll
    for (int rt = 0; rt < 2; ++rt) {
        int row = r0 + rt * 16 + l16;
        bool ok = (row < N);
        const float* xr = X + (size_t)(ok ? row : 0) * D;
        #pragma unroll
        for (int p = 0; p < 4; ++p) {
            int k0 = 32 * p + 8 * q;
            float4 a0 = ok ? *(const float4*)(xr + k0)     : make_float4(0, 0, 0, 0);
            float4 a1 = ok ? *(const float4*)(xr + k0 + 4) : make_float4(0, 0, 0, 0);
            float fv[8] = {a0.x, a0.y, a0.z, a0.w, a1.x, a1.y, a1.z, a1.w};
            bf16x8 h, l;
            #pragma unroll
            for (int e = 0; e < 8; ++e) {
                uint32_t u = __float_as_uint(fv[e]);
                h[e] = (short)(u >> 16);                             // truncate hi
                float hf = __uint_as_float(u & 0xFFFF0000u);
                l[e] = (short)(__float_as_uint(fv[e] - hf) >> 16);   // residual lo
            }
            ahi[rt][p] = h;
            alo[rt][p] = l;
        }
    }

    __syncthreads();

    // ---- MFMA main: 8 ntiles x 4 ksteps x (hi+lo) x 2 rowtiles = 128 MFMAs ----
    f32x4 acc[2][8];
    #pragma unroll
    for (int rt = 0; rt < 2; ++rt)
        #pragma unroll
        for (int j = 0; j < 8; ++j) acc[rt][j] = (f32x4){0.f, 0.f, 0.f, 0.f};

    #pragma unroll
    for (int j = 0; j < 8; ++j) {
        #pragma unroll
        for (int p = 0; p < 4; ++p) {
            bf16x8 bb = ((bf16x8*)Wf)[(j * 4 + p) * 64 + lane];
            acc[0][j] = __builtin_amdgcn_mfma_f32_16x16x32_bf16(ahi[0][p], bb, acc[0][j], 0, 0, 0);
            acc[0][j] = __builtin_amdgcn_mfma_f32_16x16x32_bf16(alo[0][p], bb, acc[0][j], 0, 0, 0);
            acc[1][j] = __builtin_amdgcn_mfma_f32_16x16x32_bf16(ahi[1][p], bb, acc[1][j], 0, 0, 0);
            acc[1][j] = __builtin_amdgcn_mfma_f32_16x16x32_bf16(alo[1][p], bb, acc[1][j], 0, 0, 0);
        }
    }

    // ---- epilogue: bias, row L2 norm (16-lane butterfly), scale, bf16 store ----
    float bias[8];
    #pragma unroll
    for (int j = 0; j < 8; ++j) bias[j] = b[16 * j + l16];

    #pragma unroll
    for (int rt = 0; rt < 2; ++rt) {
        float ss[4] = {0.f, 0.f, 0.f, 0.f};
        #pragma unroll
        for (int j = 0; j < 8; ++j)
            #pragma unroll
            for (int r = 0; r < 4; ++r) {
                float v = acc[rt][j][r] + bias[j];
                acc[rt][j][r] = v;
                ss[r] += v * v;
            }
        #pragma unroll
        for (int m = 1; m <= 8; m <<= 1)
            #pragma unroll
            for (int r = 0; r < 4; ++r) ss[r] += __shfl_xor(ss[r], m);

        #pragma unroll
        for (int r = 0; r < 4; ++r) {
            int row = r0 + rt * 16 + 4 * q + r;
            if (row < N) {
                float f = NSCALE / fmaxf(sqrtf(ss[r]), NEPS) * post[row];
                #pragma unroll
                for (int j = 0; j < 8; ++j)
                    Abuf[(size_t)row * D + 16 * j + l16] = bf16_rtn(acc[rt][j][r] * f);
            }
        }
    }
}

// ---------------- CSR gather-aggregate (bf16 in, fp32 out) ----------------
// out[n] = norm_in[n] * sum_{e in row n} A[src[e]]; 32 lanes/node, 4 cols/lane.
__global__ __launch_bounds__(256) void agg_kernel(const ushort* __restrict__ A,
                                                  const int* __restrict__ sorted_src,
                                                  const int* __restrict__ offs,
                                                  const int* __restrict__ cnt,
                                                  const float* __restrict__ norm_in,
                                                  float* __restrict__ out, int N) {
    int g = (blockIdx.x * blockDim.x + threadIdx.x) >> 5;
    int lane = threadIdx.x & 31;
    if (g >= N) return;
    int beg = offs[g];
    int len = cnt[g];
    float4 acc = make_float4(0.f, 0.f, 0.f, 0.f);
    for (int i = 0; i < len; ++i) {
        int s = sorted_src[beg + i];
        ushort4 v = *(const ushort4*)(A + (size_t)s * D + lane * 4);
        acc.x += __uint_as_float((uint32_t)v.x << 16);
        acc.y += __uint_as_float((uint32_t)v.y << 16);
        acc.z += __uint_as_float((uint32_t)v.z << 16);
        acc.w += __uint_as_float((uint32_t)v.w << 16);
    }
    float sc = norm_in[g];
    acc.x *= sc; acc.y *= sc; acc.z *= sc; acc.w *= sc;
    *(float4*)(out + (size_t)g * D + lane * 4) = acc;
}

// ---------------- launch ----------------

extern "C" void kernel_launch(void* const* d_in, const int* in_sizes, int n_in,
                              void* d_out, int out_size, void* d_ws, size_t ws_size,
                              hipStream_t stream) {
    const float* x  = (const float*)d_in[0];
    const float* W1 = (const float*)d_in[1];
    const float* b1 = (const float*)d_in[2];
    const float* W2 = (const float*)d_in[3];
    const float* b2 = (const float*)d_in[4];
    const int* src  = (const int*)d_in[5];
    const int* dst  = (const int*)d_in[6];
    float* out = (float*)d_out;

    const int N  = in_sizes[0] / D;   // 100000
    const int NE = in_sizes[5];       // 1600000
    const int NB = (N + 255) / 256;   // scan blocks (391 <= 512)

    // workspace layout (256B aligned)
    char* w = (char*)d_ws;
    auto take = [&](size_t bytes) { char* p = w; w += (bytes + 255) & ~(size_t)255; return p; };
    int*    cnt_src  = (int*)take((size_t)N * 4);
    int*    cnt_dst  = (int*)take((size_t)N * 4);
    int*    cursor   = (int*)take((size_t)N * 4);
    int*    offs     = (int*)take((size_t)N * 4);
    int*    bsum     = (int*)take((size_t)NB * 4);
    float*  norm_out = (float*)take((size_t)N * 4);
    float*  norm_in  = (float*)take((size_t)N * 4);
    int*    ssrc     = (int*)take((size_t)NE * 4);
    ushort* Abuf     = (ushort*)take((size_t)N * D * 2);

    // zero cnt_src, cnt_dst, cursor (contiguous aligned region)
    size_t zero_bytes = (char*)offs - (char*)cnt_src;
    int zn4 = (int)(zero_bytes / 16);
    zero_kernel<<<(zn4 + 255) / 256, 256, 0, stream>>>((float*)cnt_src, zn4);

    hist_kernel<<<(NE + 255) / 256, 256, 0, stream>>>(src, dst, cnt_src, cnt_dst, NE);
    norm_kernel<<<(N + 255) / 256, 256, 0, stream>>>(cnt_src, cnt_dst, norm_out, norm_in, N);

    scan1_kernel<<<NB, 256, 0, stream>>>(cnt_dst, offs, bsum, N);
    scan2_kernel<<<1, 512, 0, stream>>>(bsum, NB);
    scan3_kernel<<<NB, 256, 0, stream>>>(offs, bsum, N);

    bucket_kernel<<<(NE + 255) / 256, 256, 0, stream>>>(src, dst, offs, cursor, ssrc, NE);

    const int mlp_blocks = (N + 127) / 128;
    const int agg_blocks = (N * 32 + 255) / 256;

    // layer 1: mlp(x) -> Abuf(bf16); agg -> h1 fp32 in d_out
    mlp_mfma_kernel<<<mlp_blocks, 256, 0, stream>>>(x, W1, b1, norm_out, Abuf, N);
    agg_kernel<<<agg_blocks, 256, 0, stream>>>(Abuf, ssrc, offs, cnt_dst, norm_in, out, N);

    // layer 2: mlp(h1) -> Abuf(bf16); agg -> final fp32 in d_out
    mlp_mfma_kernel<<<mlp_blocks, 256, 0, stream>>>(out, W2, b2, norm_out, Abuf, N);
    agg_kernel<<<agg_blocks, 256, 0, stream>>>(Abuf, ssrc, offs, cnt_dst, norm_in, out, N);
}

// Round 4
// 457.731 us; speedup vs baseline: 12.8537x; 1.2498x over previous
//
#include <hip/hip_runtime.h>
#include <cstdint>
#include <cstddef>

#define D 128
#define NSCALE 1.8f
#define NEPS 1e-12f

typedef __attribute__((ext_vector_type(8))) short bf16x8;
typedef __attribute__((ext_vector_type(4))) float f32x4;

__device__ __forceinline__ ushort bf16_rtn(float f) {
    uint32_t u = __float_as_uint(f);
    u = u + 0x7FFFu + ((u >> 16) & 1u);
    return (ushort)(u >> 16);
}

__device__ __forceinline__ float bf16_to_f(ushort u) {
    return __uint_as_float((uint32_t)u << 16);
}

// ---------------- utility kernels ----------------

__global__ __launch_bounds__(256) void zero_kernel(float* __restrict__ p, int n4) {
    int i = blockIdx.x * blockDim.x + threadIdx.x;
    if (i < n4) ((float4*)p)[i] = make_float4(0.f, 0.f, 0.f, 0.f);
}

// histograms of src and dst; capture per-edge rank within its dst row
__global__ __launch_bounds__(256) void hist_kernel(const int* __restrict__ src,
                                                   const int* __restrict__ dst,
                                                   int* __restrict__ cnt_src,
                                                   int* __restrict__ cnt_dst,
                                                   int* __restrict__ seq, int ne) {
    int e = blockIdx.x * blockDim.x + threadIdx.x;
    if (e < ne) {
        atomicAdd(cnt_src + src[e], 1);
        seq[e] = atomicAdd(cnt_dst + dst[e], 1);
    }
}

// ---------------- exclusive scan (3-phase) + norm computation ----------------

__global__ __launch_bounds__(256) void scan1_kernel(const int* __restrict__ cnt,
                                                    const int* __restrict__ cnt_src,
                                                    int* __restrict__ excl,
                                                    int* __restrict__ bsum,
                                                    float* __restrict__ norm_out,
                                                    float* __restrict__ norm_in, int n) {
    __shared__ int s[256];
    int i = blockIdx.x * 256 + threadIdx.x;
    int v = (i < n) ? cnt[i] : 0;
    s[threadIdx.x] = v;
    __syncthreads();
    #pragma unroll
    for (int off = 1; off < 256; off <<= 1) {
        int t = (threadIdx.x >= off) ? s[threadIdx.x - off] : 0;
        __syncthreads();
        s[threadIdx.x] += t;
        __syncthreads();
    }
    if (i < n) {
        excl[i] = s[threadIdx.x] - v;
        norm_in[i]  = rsqrtf((float)max(v, 1));
        norm_out[i] = rsqrtf((float)max(cnt_src[i], 1));
    }
    if (threadIdx.x == 255) bsum[blockIdx.x] = s[255];
}

// block-parallel exclusive scan of bsum (nb <= 512)
__global__ __launch_bounds__(512) void scan2_kernel(int* __restrict__ bsum, int nb) {
    __shared__ int s[512];
    int t = threadIdx.x;
    int v = (t < nb) ? bsum[t] : 0;
    s[t] = v;
    __syncthreads();
    #pragma unroll
    for (int off = 1; off < 512; off <<= 1) {
        int u = (t >= off) ? s[t - off] : 0;
        __syncthreads();
        s[t] += u;
        __syncthreads();
    }
    if (t < nb) bsum[t] = s[t] - v;
}

__global__ __launch_bounds__(256) void scan3_kernel(int* __restrict__ excl,
                                                    const int* __restrict__ bsum, int n) {
    int i = blockIdx.x * 256 + threadIdx.x;
    if (i < n) excl[i] += bsum[blockIdx.x];
}

// ---------------- bucket edges into CSR order by dst (no atomics) ----------------

__global__ __launch_bounds__(256) void bucket_kernel(const int* __restrict__ src,
                                                     const int* __restrict__ dst,
                                                     const int* __restrict__ offs,
                                                     const int* __restrict__ seq,
                                                     int* __restrict__ sorted_src, int ne) {
    int e = blockIdx.x * blockDim.x + threadIdx.x;
    if (e < ne) {
        sorted_src[offs[dst[e]] + seq[e]] = src[e];
    }
}

// ---------------- MFMA MLP: out = bf16( norm_out * 1.8 * L2rownorm(X@W^T + b) ) ----
// X fp32 [N,128]; split in-registers to bf16 hi+lo (exact). W fp32 [128,128] cast
// RTN-bf16 into LDS in B-fragment order. 256 thr = 4 waves; wave = 32 rows.
__global__ __launch_bounds__(256) void mlp_mfma_kernel(const float* __restrict__ X,
                                                       const float* __restrict__ W,
                                                       const float* __restrict__ b,
                                                       const float* __restrict__ post,
                                                       ushort* __restrict__ Abuf, int N) {
    __shared__ ushort Wf[128 * 128];   // 32 KB, fragment-ordered

    const int t = threadIdx.x;
    const int wave = t >> 6;
    const int lane = t & 63;
    const int q = lane >> 4;           // quad 0..3
    const int l16 = lane & 15;

    // ---- stage W into LDS in B-fragment order, RTN bf16 ----
    #pragma unroll
    for (int it = 0; it < 8; ++it) {
        int f = t + 256 * it;          // 16B chunk id, 0..2047
        int j = f >> 8;                // ntile 0..7
        int p = (f >> 6) & 3;          // kstep 0..3
        int ln = f & 63;
        int n = 16 * j + (ln & 15);
        int k0 = 32 * p + 8 * (ln >> 4);
        const float* srcp = W + n * D + k0;
        float4 a0 = *(const float4*)(srcp);
        float4 a1 = *(const float4*)(srcp + 4);
        bf16x8 v;
        v[0] = (short)bf16_rtn(a0.x); v[1] = (short)bf16_rtn(a0.y);
        v[2] = (short)bf16_rtn(a0.z); v[3] = (short)bf16_rtn(a0.w);
        v[4] = (short)bf16_rtn(a1.x); v[5] = (short)bf16_rtn(a1.y);
        v[6] = (short)bf16_rtn(a1.z); v[7] = (short)bf16_rtn(a1.w);
        ((bf16x8*)Wf)[f] = v;
    }

    // ---- load A fragments: 2 row-tiles (32 rows), split hi/lo ----
    const int r0 = blockIdx.x * 128 + wave * 32;
    bf16x8 ahi[2][4], alo[2][4];
    #pragma unroll
    for (int rt = 0; rt < 2; ++rt) {
        int row = r0 + rt * 16 + l16;
        bool ok = (row < N);
        const float* xr = X + (size_t)(ok ? row : 0) * D;
        #pragma unroll
        for (int p = 0; p < 4; ++p) {
            int k0 = 32 * p + 8 * q;
            float4 a0 = ok ? *(const float4*)(xr + k0)     : make_float4(0, 0, 0, 0);
            float4 a1 = ok ? *(const float4*)(xr + k0 + 4) : make_float4(0, 0, 0, 0);
            float fv[8] = {a0.x, a0.y, a0.z, a0.w, a1.x, a1.y, a1.z, a1.w};
            bf16x8 h, l;
            #pragma unroll
            for (int e = 0; e < 8; ++e) {
                uint32_t u = __float_as_uint(fv[e]);
                h[e] = (short)(u >> 16);                             // truncate hi
                float hf = __uint_as_float(u & 0xFFFF0000u);
                l[e] = (short)(__float_as_uint(fv[e] - hf) >> 16);   // residual lo
            }
            ahi[rt][p] = h;
            alo[rt][p] = l;
        }
    }

    __syncthreads();

    // ---- MFMA main: 8 ntiles x 4 ksteps x (hi+lo) x 2 rowtiles = 128 MFMAs ----
    f32x4 acc[2][8];
    #pragma unroll
    for (int rt = 0; rt < 2; ++rt)
        #pragma unroll
        for (int j = 0; j < 8; ++j) acc[rt][j] = (f32x4){0.f, 0.f, 0.f, 0.f};

    #pragma unroll
    for (int j = 0; j < 8; ++j) {
        #pragma unroll
        for (int p = 0; p < 4; ++p) {
            bf16x8 bb = ((bf16x8*)Wf)[(j * 4 + p) * 64 + lane];
            acc[0][j] = __builtin_amdgcn_mfma_f32_16x16x32_bf16(ahi[0][p], bb, acc[0][j], 0, 0, 0);
            acc[0][j] = __builtin_amdgcn_mfma_f32_16x16x32_bf16(alo[0][p], bb, acc[0][j], 0, 0, 0);
            acc[1][j] = __builtin_amdgcn_mfma_f32_16x16x32_bf16(ahi[1][p], bb, acc[1][j], 0, 0, 0);
            acc[1][j] = __builtin_amdgcn_mfma_f32_16x16x32_bf16(alo[1][p], bb, acc[1][j], 0, 0, 0);
        }
    }

    // ---- epilogue: bias, row L2 norm (16-lane butterfly), scale, bf16 store ----
    float bias[8];
    #pragma unroll
    for (int j = 0; j < 8; ++j) bias[j] = b[16 * j + l16];

    #pragma unroll
    for (int rt = 0; rt < 2; ++rt) {
        float ss[4] = {0.f, 0.f, 0.f, 0.f};
        #pragma unroll
        for (int j = 0; j < 8; ++j)
            #pragma unroll
            for (int r = 0; r < 4; ++r) {
                float v = acc[rt][j][r] + bias[j];
                acc[rt][j][r] = v;
                ss[r] += v * v;
            }
        #pragma unroll
        for (int m = 1; m <= 8; m <<= 1)
            #pragma unroll
            for (int r = 0; r < 4; ++r) ss[r] += __shfl_xor(ss[r], m);

        #pragma unroll
        for (int r = 0; r < 4; ++r) {
            int row = r0 + rt * 16 + 4 * q + r;
            if (row < N) {
                float f = NSCALE / fmaxf(sqrtf(ss[r]), NEPS) * post[row];
                #pragma unroll
                for (int j = 0; j < 8; ++j)
                    Abuf[(size_t)row * D + 16 * j + l16] = bf16_rtn(acc[rt][j][r] * f);
            }
        }
    }
}

// ---------------- CSR gather-aggregate (bf16 in, fp32 out) ----------------
// out[n] = norm_in[n] * sum_{e in row n} A[src[e]]; 32 lanes/node, 4 cols/lane.
// 4-way unrolled so 4 independent row-gathers are in flight per wave-node.
__global__ __launch_bounds__(256) void agg_kernel(const ushort* __restrict__ A,
                                                  const int* __restrict__ sorted_src,
                                                  const int* __restrict__ offs,
                                                  const int* __restrict__ cnt,
                                                  const float* __restrict__ norm_in,
                                                  float* __restrict__ out, int N) {
    int g = (blockIdx.x * blockDim.x + threadIdx.x) >> 5;
    int lane = threadIdx.x & 31;
    if (g >= N) return;
    int beg = offs[g];
    int len = cnt[g];
    float4 acc = make_float4(0.f, 0.f, 0.f, 0.f);
    int i = 0;
    for (; i + 4 <= len; i += 4) {
        int s0 = sorted_src[beg + i];
        int s1 = sorted_src[beg + i + 1];
        int s2 = sorted_src[beg + i + 2];
        int s3 = sorted_src[beg + i + 3];
        ushort4 v0 = *(const ushort4*)(A + (size_t)s0 * D + lane * 4);
        ushort4 v1 = *(const ushort4*)(A + (size_t)s1 * D + lane * 4);
        ushort4 v2 = *(const ushort4*)(A + (size_t)s2 * D + lane * 4);
        ushort4 v3 = *(const ushort4*)(A + (size_t)s3 * D + lane * 4);
        acc.x += bf16_to_f(v0.x) + bf16_to_f(v1.x) + bf16_to_f(v2.x) + bf16_to_f(v3.x);
        acc.y += bf16_to_f(v0.y) + bf16_to_f(v1.y) + bf16_to_f(v2.y) + bf16_to_f(v3.y);
        acc.z += bf16_to_f(v0.z) + bf16_to_f(v1.z) + bf16_to_f(v2.z) + bf16_to_f(v3.z);
        acc.w += bf16_to_f(v0.w) + bf16_to_f(v1.w) + bf16_to_f(v2.w) + bf16_to_f(v3.w);
    }
    for (; i < len; ++i) {
        int s = sorted_src[beg + i];
        ushort4 v = *(const ushort4*)(A + (size_t)s * D + lane * 4);
        acc.x += bf16_to_f(v.x);
        acc.y += bf16_to_f(v.y);
        acc.z += bf16_to_f(v.z);
        acc.w += bf16_to_f(v.w);
    }
    float sc = norm_in[g];
    acc.x *= sc; acc.y *= sc; acc.z *= sc; acc.w *= sc;
    *(float4*)(out + (size_t)g * D + lane * 4) = acc;
}

// ---------------- launch ----------------

extern "C" void kernel_launch(void* const* d_in, const int* in_sizes, int n_in,
                              void* d_out, int out_size, void* d_ws, size_t ws_size,
                              hipStream_t stream) {
    const float* x  = (const float*)d_in[0];
    const float* W1 = (const float*)d_in[1];
    const float* b1 = (const float*)d_in[2];
    const float* W2 = (const float*)d_in[3];
    const float* b2 = (const float*)d_in[4];
    const int* src  = (const int*)d_in[5];
    const int* dst  = (const int*)d_in[6];
    float* out = (float*)d_out;

    const int N  = in_sizes[0] / D;   // 100000
    const int NE = in_sizes[5];       // 1600000
    const int NB = (N + 255) / 256;   // scan blocks (391 <= 512)

    // workspace layout (256B aligned)
    char* w = (char*)d_ws;
    auto take = [&](size_t bytes) { char* p = w; w += (bytes + 255) & ~(size_t)255; return p; };
    int*    cnt_src  = (int*)take((size_t)N * 4);
    int*    cnt_dst  = (int*)take((size_t)N * 4);
    int*    offs     = (int*)take((size_t)N * 4);
    int*    bsum     = (int*)take((size_t)NB * 4);
    float*  norm_out = (float*)take((size_t)N * 4);
    float*  norm_in  = (float*)take((size_t)N * 4);
    int*    seq      = (int*)take((size_t)NE * 4);
    int*    ssrc     = (int*)take((size_t)NE * 4);
    ushort* Abuf     = (ushort*)take((size_t)N * D * 2);

    // zero cnt_src + cnt_dst (contiguous aligned region)
    size_t zero_bytes = (char*)offs - (char*)cnt_src;
    int zn4 = (int)(zero_bytes / 16);
    zero_kernel<<<(zn4 + 255) / 256, 256, 0, stream>>>((float*)cnt_src, zn4);

    // histograms (+ per-edge dst-rank capture)
    hist_kernel<<<(NE + 255) / 256, 256, 0, stream>>>(src, dst, cnt_src, cnt_dst, seq, NE);

    // exclusive scan of cnt_dst -> offs ; norms computed in scan1
    scan1_kernel<<<NB, 256, 0, stream>>>(cnt_dst, cnt_src, offs, bsum, norm_out, norm_in, N);
    scan2_kernel<<<1, 512, 0, stream>>>(bsum, NB);
    scan3_kernel<<<NB, 256, 0, stream>>>(offs, bsum, N);

    // bucket edges by dst (atomic-free)
    bucket_kernel<<<(NE + 255) / 256, 256, 0, stream>>>(src, dst, offs, seq, ssrc, NE);

    const int mlp_blocks = (N + 127) / 128;
    const int agg_blocks = (N * 32 + 255) / 256;

    // layer 1: mlp(x) -> Abuf(bf16); agg -> h1 fp32 in d_out
    mlp_mfma_kernel<<<mlp_blocks, 256, 0, stream>>>(x, W1, b1, norm_out, Abuf, N);
    agg_kernel<<<agg_blocks, 256, 0, stream>>>(Abuf, ssrc, offs, cnt_dst, norm_in, out, N);

    // layer 2: mlp(h1) -> Abuf(bf16); agg -> final fp32 in d_out
    mlp_mfma_kernel<<<mlp_blocks, 256, 0, stream>>>(out, W2, b2, norm_out, Abuf, N);
    agg_kernel<<<agg_blocks, 256, 0, stream>>>(Abuf, ssrc, offs, cnt_dst, norm_in, out, N);
}

// Round 5
// 351.925 us; speedup vs baseline: 16.7181x; 1.3006x over previous
//
#include <hip/hip_runtime.h>
#include <cstdint>
#include <cstddef>

#define D 128
#define NSCALE 1.8f
#define NEPS 1e-12f
#define EPB 8192      // edges per block in the high-bucket phase
#define NLO 512       // low radix bins (dst & 511)

typedef __attribute__((ext_vector_type(8))) short bf16x8;
typedef __attribute__((ext_vector_type(4))) float f32x4;

__device__ __forceinline__ ushort bf16_rtn(float f) {
    uint32_t u = __float_as_uint(f);
    u = u + 0x7FFFu + ((u >> 16) & 1u);
    return (ushort)(u >> 16);
}

__device__ __forceinline__ float bf16_to_f(ushort u) {
    return __uint_as_float((uint32_t)u << 16);
}

// ---------------- K1: per-block LDS histograms of high bits ----------------
__global__ __launch_bounds__(256) void hist_high_kernel(const int* __restrict__ src,
                                                        const int* __restrict__ dst,
                                                        int* __restrict__ Hd,
                                                        int* __restrict__ Hs, int ne) {
    __shared__ int hd[256], hs[256];
    int t = threadIdx.x, b = blockIdx.x;
    hd[t] = 0; hs[t] = 0;
    __syncthreads();
    int base = b * EPB, end = min(ne, base + EPB);
    for (int i = base + t; i < end; i += 256) {
        atomicAdd(&hd[dst[i] >> 9], 1);
        atomicAdd(&hs[src[i] >> 9], 1);
    }
    __syncthreads();
    Hd[b * 256 + t] = hd[t];
    Hs[b * 256 + t] = hs[t];
}

// ---------------- K2a: exclusive scan down each bucket column ----------------
__global__ __launch_bounds__(256) void scan_cols_kernel(int* __restrict__ Hd,
                                                        int* __restrict__ Hs,
                                                        int* __restrict__ total_d,
                                                        int* __restrict__ total_s, int nbk) {
    __shared__ int s[256];
    int* H = blockIdx.y ? Hs : Hd;
    int* tot = blockIdx.y ? total_s : total_d;
    int v = blockIdx.x, t = threadIdx.x;
    int val = (t < nbk) ? H[t * 256 + v] : 0;
    s[t] = val;
    __syncthreads();
    #pragma unroll
    for (int off = 1; off < 256; off <<= 1) {
        int u = (t >= off) ? s[t - off] : 0;
        __syncthreads();
        s[t] += u;
        __syncthreads();
    }
    if (t < nbk) H[t * 256 + v] = s[t] - val;   // exclusive within column
    if (t == nbk - 1) tot[v] = s[t];
}

// ---------------- K2b: exclusive scan of bucket totals -> bucket bases ----------------
__global__ __launch_bounds__(256) void scan_tot_kernel(const int* __restrict__ total_d,
                                                       const int* __restrict__ total_s,
                                                       int* __restrict__ Bd,
                                                       int* __restrict__ Bs, int hb) {
    __shared__ int s[256];
    const int* tot = blockIdx.x ? total_s : total_d;
    int* B = blockIdx.x ? Bs : Bd;
    int t = threadIdx.x;
    int val = (t < hb) ? tot[t] : 0;
    s[t] = val;
    __syncthreads();
    #pragma unroll
    for (int off = 1; off < 256; off <<= 1) {
        int u = (t >= off) ? s[t - off] : 0;
        __syncthreads();
        s[t] += u;
        __syncthreads();
    }
    if (t <= hb) B[t] = s[t] - val;   // B[hb] = total edge count
}

// ---------------- K3: scatter edges into high buckets (LDS cursors only) ----------------
__global__ __launch_bounds__(256) void scatter_high_kernel(const int* __restrict__ src,
                                                           const int* __restrict__ dst,
                                                           const int* __restrict__ Hd,
                                                           const int* __restrict__ Hs,
                                                           const int* __restrict__ Bd,
                                                           const int* __restrict__ Bs,
                                                           int* __restrict__ sd_dst,
                                                           int* __restrict__ sd_src,
                                                           int* __restrict__ ss_src,
                                                           int ne, int hb) {
    __shared__ int cur_d[256], cur_s[256];
    int t = threadIdx.x, b = blockIdx.x;
    if (t < hb) {
        cur_d[t] = Bd[t] + Hd[b * 256 + t];
        cur_s[t] = Bs[t] + Hs[b * 256 + t];
    }
    __syncthreads();
    int base = b * EPB, end = min(ne, base + EPB);
    for (int i = base + t; i < end; i += 256) {
        int d = dst[i], s = src[i];
        int pd = atomicAdd(&cur_d[d >> 9], 1);
        sd_dst[pd] = d;
        sd_src[pd] = s;
        int ps = atomicAdd(&cur_s[s >> 9], 1);
        ss_src[ps] = s;
    }
}

// ---------------- K4a: per-bucket counting sort by low bits; emit CSR + norms ----
__global__ __launch_bounds__(512) void bucket_sort_kernel(const int* __restrict__ sd_dst,
                                                          const int* __restrict__ sd_src,
                                                          const int* __restrict__ Bd,
                                                          int* __restrict__ offs,
                                                          int* __restrict__ cnt_dst,
                                                          float* __restrict__ norm_in,
                                                          int* __restrict__ ssrc, int N) {
    __shared__ int h[NLO], sc[NLO], cur[NLO];
    int t = threadIdx.x, v = blockIdx.x;
    int beg = Bd[v], end = Bd[v + 1];
    h[t] = 0;
    __syncthreads();
    for (int i = beg + t; i < end; i += 512) atomicAdd(&h[sd_dst[i] & (NLO - 1)], 1);
    __syncthreads();
    int cnt = h[t];
    sc[t] = cnt;
    __syncthreads();
    #pragma unroll
    for (int off = 1; off < NLO; off <<= 1) {
        int u = (t >= off) ? sc[t - off] : 0;
        __syncthreads();
        sc[t] += u;
        __syncthreads();
    }
    int excl = sc[t] - cnt;
    int g = (v << 9) + t;
    if (g < N) {
        offs[g] = beg + excl;
        cnt_dst[g] = cnt;
        norm_in[g] = rsqrtf((float)max(cnt, 1));
    }
    cur[t] = beg + excl;
    __syncthreads();
    for (int i = beg + t; i < end; i += 512) {
        int d = sd_dst[i];
        int s = sd_src[i];
        int p = atomicAdd(&cur[d & (NLO - 1)], 1);
        ssrc[p] = s;
    }
}

// ---------------- K4b: per-bucket hist of src low bits -> norm_out ----------------
__global__ __launch_bounds__(512) void bucket_hist_kernel(const int* __restrict__ ss_src,
                                                          const int* __restrict__ Bs,
                                                          float* __restrict__ norm_out, int N) {
    __shared__ int h[NLO];
    int t = threadIdx.x, v = blockIdx.x;
    int beg = Bs[v], end = Bs[v + 1];
    h[t] = 0;
    __syncthreads();
    for (int i = beg + t; i < end; i += 512) atomicAdd(&h[ss_src[i] & (NLO - 1)], 1);
    __syncthreads();
    int g = (v << 9) + t;
    if (g < N) norm_out[g] = rsqrtf((float)max(h[t], 1));
}

// ---------------- MFMA MLP: out = bf16( norm_out * 1.8 * L2rownorm(X@W^T + b) ) ----
__global__ __launch_bounds__(256) void mlp_mfma_kernel(const float* __restrict__ X,
                                                       const float* __restrict__ W,
                                                       const float* __restrict__ b,
                                                       const float* __restrict__ post,
                                                       ushort* __restrict__ Abuf, int N) {
    __shared__ ushort Wf[128 * 128];   // 32 KB, fragment-ordered

    const int t = threadIdx.x;
    const int wave = t >> 6;
    const int lane = t & 63;
    const int q = lane >> 4;           // quad 0..3
    const int l16 = lane & 15;

    #pragma unroll
    for (int it = 0; it < 8; ++it) {
        int f = t + 256 * it;          // 16B chunk id, 0..2047
        int j = f >> 8;                // ntile 0..7
        int p = (f >> 6) & 3;          // kstep 0..3
        int ln = f & 63;
        int n = 16 * j + (ln & 15);
        int k0 = 32 * p + 8 * (ln >> 4);
        const float* srcp = W + n * D + k0;
        float4 a0 = *(const float4*)(srcp);
        float4 a1 = *(const float4*)(srcp + 4);
        bf16x8 v;
        v[0] = (short)bf16_rtn(a0.x); v[1] = (short)bf16_rtn(a0.y);
        v[2] = (short)bf16_rtn(a0.z); v[3] = (short)bf16_rtn(a0.w);
        v[4] = (short)bf16_rtn(a1.x); v[5] = (short)bf16_rtn(a1.y);
        v[6] = (short)bf16_rtn(a1.z); v[7] = (short)bf16_rtn(a1.w);
        ((bf16x8*)Wf)[f] = v;
    }

    const int r0 = blockIdx.x * 128 + wave * 32;
    bf16x8 ahi[2][4], alo[2][4];
    #pragma unroll
    for (int rt = 0; rt < 2; ++rt) {
        int row = r0 + rt * 16 + l16;
        bool ok = (row < N);
        const float* xr = X + (size_t)(ok ? row : 0) * D;
        #pragma unroll
        for (int p = 0; p < 4; ++p) {
            int k0 = 32 * p + 8 * q;
            float4 a0 = ok ? *(const float4*)(xr + k0)     : make_float4(0, 0, 0, 0);
            float4 a1 = ok ? *(const float4*)(xr + k0 + 4) : make_float4(0, 0, 0, 0);
            float fv[8] = {a0.x, a0.y, a0.z, a0.w, a1.x, a1.y, a1.z, a1.w};
            bf16x8 h, l;
            #pragma unroll
            for (int e = 0; e < 8; ++e) {
                uint32_t u = __float_as_uint(fv[e]);
                h[e] = (short)(u >> 16);
                float hf = __uint_as_float(u & 0xFFFF0000u);
                l[e] = (short)(__float_as_uint(fv[e] - hf) >> 16);
            }
            ahi[rt][p] = h;
            alo[rt][p] = l;
        }
    }

    __syncthreads();

    f32x4 acc[2][8];
    #pragma unroll
    for (int rt = 0; rt < 2; ++rt)
        #pragma unroll
        for (int j = 0; j < 8; ++j) acc[rt][j] = (f32x4){0.f, 0.f, 0.f, 0.f};

    #pragma unroll
    for (int j = 0; j < 8; ++j) {
        #pragma unroll
        for (int p = 0; p < 4; ++p) {
            bf16x8 bb = ((bf16x8*)Wf)[(j * 4 + p) * 64 + lane];
            acc[0][j] = __builtin_amdgcn_mfma_f32_16x16x32_bf16(ahi[0][p], bb, acc[0][j], 0, 0, 0);
            acc[0][j] = __builtin_amdgcn_mfma_f32_16x16x32_bf16(alo[0][p], bb, acc[0][j], 0, 0, 0);
            acc[1][j] = __builtin_amdgcn_mfma_f32_16x16x32_bf16(ahi[1][p], bb, acc[1][j], 0, 0, 0);
            acc[1][j] = __builtin_amdgcn_mfma_f32_16x16x32_bf16(alo[1][p], bb, acc[1][j], 0, 0, 0);
        }
    }

    float bias[8];
    #pragma unroll
    for (int j = 0; j < 8; ++j) bias[j] = b[16 * j + l16];

    #pragma unroll
    for (int rt = 0; rt < 2; ++rt) {
        float ss[4] = {0.f, 0.f, 0.f, 0.f};
        #pragma unroll
        for (int j = 0; j < 8; ++j)
            #pragma unroll
            for (int r = 0; r < 4; ++r) {
                float v = acc[rt][j][r] + bias[j];
                acc[rt][j][r] = v;
                ss[r] += v * v;
            }
        #pragma unroll
        for (int m = 1; m <= 8; m <<= 1)
            #pragma unroll
            for (int r = 0; r < 4; ++r) ss[r] += __shfl_xor(ss[r], m);

        #pragma unroll
        for (int r = 0; r < 4; ++r) {
            int row = r0 + rt * 16 + 4 * q + r;
            if (row < N) {
                float f = NSCALE / fmaxf(sqrtf(ss[r]), NEPS) * post[row];
                #pragma unroll
                for (int j = 0; j < 8; ++j)
                    Abuf[(size_t)row * D + 16 * j + l16] = bf16_rtn(acc[rt][j][r] * f);
            }
        }
    }
}

// ---------------- CSR gather-aggregate (bf16 in, fp32 out) ----------------
__global__ __launch_bounds__(256) void agg_kernel(const ushort* __restrict__ A,
                                                  const int* __restrict__ sorted_src,
                                                  const int* __restrict__ offs,
                                                  const int* __restrict__ cnt,
                                                  const float* __restrict__ norm_in,
                                                  float* __restrict__ out, int N) {
    int g = (blockIdx.x * blockDim.x + threadIdx.x) >> 5;
    int lane = threadIdx.x & 31;
    if (g >= N) return;
    int beg = offs[g];
    int len = cnt[g];
    float4 acc = make_float4(0.f, 0.f, 0.f, 0.f);
    int i = 0;
    for (; i + 4 <= len; i += 4) {
        int s0 = sorted_src[beg + i];
        int s1 = sorted_src[beg + i + 1];
        int s2 = sorted_src[beg + i + 2];
        int s3 = sorted_src[beg + i + 3];
        ushort4 v0 = *(const ushort4*)(A + (size_t)s0 * D + lane * 4);
        ushort4 v1 = *(const ushort4*)(A + (size_t)s1 * D + lane * 4);
        ushort4 v2 = *(const ushort4*)(A + (size_t)s2 * D + lane * 4);
        ushort4 v3 = *(const ushort4*)(A + (size_t)s3 * D + lane * 4);
        acc.x += bf16_to_f(v0.x) + bf16_to_f(v1.x) + bf16_to_f(v2.x) + bf16_to_f(v3.x);
        acc.y += bf16_to_f(v0.y) + bf16_to_f(v1.y) + bf16_to_f(v2.y) + bf16_to_f(v3.y);
        acc.z += bf16_to_f(v0.z) + bf16_to_f(v1.z) + bf16_to_f(v2.z) + bf16_to_f(v3.z);
        acc.w += bf16_to_f(v0.w) + bf16_to_f(v1.w) + bf16_to_f(v2.w) + bf16_to_f(v3.w);
    }
    for (; i < len; ++i) {
        int s = sorted_src[beg + i];
        ushort4 v = *(const ushort4*)(A + (size_t)s * D + lane * 4);
        acc.x += bf16_to_f(v.x);
        acc.y += bf16_to_f(v.y);
        acc.z += bf16_to_f(v.z);
        acc.w += bf16_to_f(v.w);
    }
    float sc = norm_in[g];
    acc.x *= sc; acc.y *= sc; acc.z *= sc; acc.w *= sc;
    *(float4*)(out + (size_t)g * D + lane * 4) = acc;
}

// ---------------- launch ----------------

extern "C" void kernel_launch(void* const* d_in, const int* in_sizes, int n_in,
                              void* d_out, int out_size, void* d_ws, size_t ws_size,
                              hipStream_t stream) {
    const float* x  = (const float*)d_in[0];
    const float* W1 = (const float*)d_in[1];
    const float* b1 = (const float*)d_in[2];
    const float* W2 = (const float*)d_in[3];
    const float* b2 = (const float*)d_in[4];
    const int* src  = (const int*)d_in[5];
    const int* dst  = (const int*)d_in[6];
    float* out = (float*)d_out;

    const int N  = in_sizes[0] / D;        // 100000
    const int NE = in_sizes[5];            // 1600000
    const int NBK = (NE + EPB - 1) / EPB;  // 196  (must be <= 256)
    const int HB  = (N + NLO - 1) / NLO;   // 196  (must be <= 255)

    // workspace layout (256B aligned)
    char* w = (char*)d_ws;
    auto take = [&](size_t bytes) { char* p = w; w += (bytes + 255) & ~(size_t)255; return p; };
    int*    Hd       = (int*)take((size_t)NBK * 256 * 4);
    int*    Hs       = (int*)take((size_t)NBK * 256 * 4);
    int*    total_d  = (int*)take(256 * 4);
    int*    total_s  = (int*)take(256 * 4);
    int*    Bd       = (int*)take((size_t)(HB + 1) * 4);
    int*    Bs       = (int*)take((size_t)(HB + 1) * 4);
    int*    sd_dst   = (int*)take((size_t)NE * 4);
    int*    sd_src   = (int*)take((size_t)NE * 4);
    int*    ss_src   = (int*)take((size_t)NE * 4);
    int*    ssrc     = (int*)take((size_t)NE * 4);
    int*    offs     = (int*)take((size_t)N * 4);
    int*    cnt_dst  = (int*)take((size_t)N * 4);
    float*  norm_in  = (float*)take((size_t)N * 4);
    float*  norm_out = (float*)take((size_t)N * 4);
    ushort* Abuf     = (ushort*)take((size_t)N * D * 2);

    // atomic-free MSB counting sort + degree norms
    hist_high_kernel<<<NBK, 256, 0, stream>>>(src, dst, Hd, Hs, NE);
    scan_cols_kernel<<<dim3(HB, 2), 256, 0, stream>>>(Hd, Hs, total_d, total_s, NBK);
    scan_tot_kernel<<<2, 256, 0, stream>>>(total_d, total_s, Bd, Bs, HB);
    scatter_high_kernel<<<NBK, 256, 0, stream>>>(src, dst, Hd, Hs, Bd, Bs,
                                                 sd_dst, sd_src, ss_src, NE, HB);
    bucket_sort_kernel<<<HB, 512, 0, stream>>>(sd_dst, sd_src, Bd, offs, cnt_dst,
                                               norm_in, ssrc, N);
    bucket_hist_kernel<<<HB, 512, 0, stream>>>(ss_src, Bs, norm_out, N);

    const int mlp_blocks = (N + 127) / 128;
    const int agg_blocks = (N * 32 + 255) / 256;

    // layer 1: mlp(x) -> Abuf(bf16); agg -> h1 fp32 in d_out
    mlp_mfma_kernel<<<mlp_blocks, 256, 0, stream>>>(x, W1, b1, norm_out, Abuf, N);
    agg_kernel<<<agg_blocks, 256, 0, stream>>>(Abuf, ssrc, offs, cnt_dst, norm_in, out, N);

    // layer 2: mlp(h1) -> Abuf(bf16); agg -> final fp32 in d_out
    mlp_mfma_kernel<<<mlp_blocks, 256, 0, stream>>>(out, W2, b2, norm_out, Abuf, N);
    agg_kernel<<<agg_blocks, 256, 0, stream>>>(Abuf, ssrc, offs, cnt_dst, norm_in, out, N);
}

// Round 6
// 341.798 us; speedup vs baseline: 17.2135x; 1.0296x over previous
//
#include <hip/hip_runtime.h>
#include <cstdint>
#include <cstddef>

#define D 128
#define NSCALE 1.8f
#define NEPS 1e-12f
#define EPB 8192      // edges per block in the high-bucket phase
#define NLO 512       // low radix bins (dst & 511)
#define SCAP 9216     // LDS staging capacity for bucket_sort (ints)

typedef __attribute__((ext_vector_type(8))) short bf16x8;
typedef __attribute__((ext_vector_type(8))) unsigned short u16x8;
typedef __attribute__((ext_vector_type(4))) float f32x4;

__device__ __forceinline__ ushort bf16_rtn(float f) {
    uint32_t u = __float_as_uint(f);
    u = u + 0x7FFFu + ((u >> 16) & 1u);
    return (ushort)(u >> 16);
}

__device__ __forceinline__ float bf16_to_f(ushort u) {
    return __uint_as_float((uint32_t)u << 16);
}

// ---------------- K1: per-block LDS histograms of high bits ----------------
__global__ __launch_bounds__(256) void hist_high_kernel(const int* __restrict__ src,
                                                        const int* __restrict__ dst,
                                                        int* __restrict__ Hd,
                                                        int* __restrict__ Hs, int ne) {
    __shared__ int hd[256], hs[256];
    int t = threadIdx.x, b = blockIdx.x;
    hd[t] = 0; hs[t] = 0;
    __syncthreads();
    int base = b * EPB, end = min(ne, base + EPB);
    for (int i = base + t; i < end; i += 256) {
        atomicAdd(&hd[dst[i] >> 9], 1);
        atomicAdd(&hs[src[i] >> 9], 1);
    }
    __syncthreads();
    Hd[b * 256 + t] = hd[t];
    Hs[b * 256 + t] = hs[t];
}

// ---------------- K2a: exclusive scan down each bucket column ----------------
__global__ __launch_bounds__(256) void scan_cols_kernel(int* __restrict__ Hd,
                                                        int* __restrict__ Hs,
                                                        int* __restrict__ total_d,
                                                        int* __restrict__ total_s, int nbk) {
    __shared__ int s[256];
    int* H = blockIdx.y ? Hs : Hd;
    int* tot = blockIdx.y ? total_s : total_d;
    int v = blockIdx.x, t = threadIdx.x;
    int val = (t < nbk) ? H[t * 256 + v] : 0;
    s[t] = val;
    __syncthreads();
    #pragma unroll
    for (int off = 1; off < 256; off <<= 1) {
        int u = (t >= off) ? s[t - off] : 0;
        __syncthreads();
        s[t] += u;
        __syncthreads();
    }
    if (t < nbk) H[t * 256 + v] = s[t] - val;   // exclusive within column
    if (t == nbk - 1) tot[v] = s[t];
}

// ---------------- K2b: exclusive scan of bucket totals -> bucket bases ----------------
__global__ __launch_bounds__(256) void scan_tot_kernel(const int* __restrict__ total_d,
                                                       const int* __restrict__ total_s,
                                                       int* __restrict__ Bd,
                                                       int* __restrict__ Bs, int hb) {
    __shared__ int s[256];
    const int* tot = blockIdx.x ? total_s : total_d;
    int* B = blockIdx.x ? Bs : Bd;
    int t = threadIdx.x;
    int val = (t < hb) ? tot[t] : 0;
    s[t] = val;
    __syncthreads();
    #pragma unroll
    for (int off = 1; off < 256; off <<= 1) {
        int u = (t >= off) ? s[t - off] : 0;
        __syncthreads();
        s[t] += u;
        __syncthreads();
    }
    if (t <= hb) B[t] = s[t] - val;   // B[hb] = total edge count
}

// ---------------- K3: scatter edges into high buckets (LDS cursors, packed pairs) ----
__global__ __launch_bounds__(256) void scatter_high_kernel(const int* __restrict__ src,
                                                           const int* __restrict__ dst,
                                                           const int* __restrict__ Hd,
                                                           const int* __restrict__ Hs,
                                                           const int* __restrict__ Bd,
                                                           const int* __restrict__ Bs,
                                                           int2* __restrict__ sd_pair,
                                                           int* __restrict__ ss_src,
                                                           int ne, int hb) {
    __shared__ int cur_d[256], cur_s[256];
    int t = threadIdx.x, b = blockIdx.x;
    if (t < hb) {
        cur_d[t] = Bd[t] + Hd[b * 256 + t];
        cur_s[t] = Bs[t] + Hs[b * 256 + t];
    }
    __syncthreads();
    int base = b * EPB, end = min(ne, base + EPB);
    for (int i = base + t; i < end; i += 256) {
        int d = dst[i], s = src[i];
        int pd = atomicAdd(&cur_d[d >> 9], 1);
        sd_pair[pd] = make_int2(d, s);
        int ps = atomicAdd(&cur_s[s >> 9], 1);
        ss_src[ps] = s;
    }
}

// ---------------- K4a: per-bucket counting sort by low bits; emit CSR + norms ----
// Final ssrc writes staged through LDS so global writes are coalesced.
__global__ __launch_bounds__(512) void bucket_sort_kernel(const int2* __restrict__ sd_pair,
                                                          const int* __restrict__ Bd,
                                                          int* __restrict__ offs,
                                                          int* __restrict__ cnt_dst,
                                                          float* __restrict__ norm_in,
                                                          int* __restrict__ ssrc, int N) {
    __shared__ int h[NLO], sc[NLO], cur[NLO];
    __shared__ int stage[SCAP];
    int t = threadIdx.x, v = blockIdx.x;
    int beg = Bd[v], end = Bd[v + 1];
    int m = end - beg;
    h[t] = 0;
    __syncthreads();
    for (int i = beg + t; i < end; i += 512) atomicAdd(&h[sd_pair[i].x & (NLO - 1)], 1);
    __syncthreads();
    int cnt = h[t];
    sc[t] = cnt;
    __syncthreads();
    #pragma unroll
    for (int off = 1; off < NLO; off <<= 1) {
        int u = (t >= off) ? sc[t - off] : 0;
        __syncthreads();
        sc[t] += u;
        __syncthreads();
    }
    int excl = sc[t] - cnt;
    int g = (v << 9) + t;
    if (g < N) {
        offs[g] = beg + excl;
        cnt_dst[g] = cnt;
        norm_in[g] = rsqrtf((float)max(cnt, 1));
    }
    if (m <= SCAP) {
        cur[t] = excl;
        __syncthreads();
        for (int i = beg + t; i < end; i += 512) {
            int2 p = sd_pair[i];
            int pos = atomicAdd(&cur[p.x & (NLO - 1)], 1);
            stage[pos] = p.y;
        }
        __syncthreads();
        for (int j = t; j < m; j += 512) ssrc[beg + j] = stage[j];
    } else {
        cur[t] = beg + excl;
        __syncthreads();
        for (int i = beg + t; i < end; i += 512) {
            int2 p = sd_pair[i];
            int pos = atomicAdd(&cur[p.x & (NLO - 1)], 1);
            ssrc[pos] = p.y;
        }
    }
}

// ---------------- K4b: per-bucket hist of src low bits -> norm_out ----------------
__global__ __launch_bounds__(512) void bucket_hist_kernel(const int* __restrict__ ss_src,
                                                          const int* __restrict__ Bs,
                                                          float* __restrict__ norm_out, int N) {
    __shared__ int h[NLO];
    int t = threadIdx.x, v = blockIdx.x;
    int beg = Bs[v], end = Bs[v + 1];
    h[t] = 0;
    __syncthreads();
    for (int i = beg + t; i < end; i += 512) atomicAdd(&h[ss_src[i] & (NLO - 1)], 1);
    __syncthreads();
    int g = (v << 9) + t;
    if (g < N) norm_out[g] = rsqrtf((float)max(h[t], 1));
}

// ---------------- MFMA MLP: out = bf16( norm_out * 1.8 * L2rownorm(X@W^T + b) ) ----
__global__ __launch_bounds__(256) void mlp_mfma_kernel(const float* __restrict__ X,
                                                       const float* __restrict__ W,
                                                       const float* __restrict__ b,
                                                       const float* __restrict__ post,
                                                       ushort* __restrict__ Abuf, int N) {
    __shared__ ushort Wf[128 * 128];   // 32 KB, fragment-ordered

    const int t = threadIdx.x;
    const int wave = t >> 6;
    const int lane = t & 63;
    const int q = lane >> 4;           // quad 0..3
    const int l16 = lane & 15;

    #pragma unroll
    for (int it = 0; it < 8; ++it) {
        int f = t + 256 * it;          // 16B chunk id, 0..2047
        int j = f >> 8;                // ntile 0..7
        int p = (f >> 6) & 3;          // kstep 0..3
        int ln = f & 63;
        int n = 16 * j + (ln & 15);
        int k0 = 32 * p + 8 * (ln >> 4);
        const float* srcp = W + n * D + k0;
        float4 a0 = *(const float4*)(srcp);
        float4 a1 = *(const float4*)(srcp + 4);
        bf16x8 v;
        v[0] = (short)bf16_rtn(a0.x); v[1] = (short)bf16_rtn(a0.y);
        v[2] = (short)bf16_rtn(a0.z); v[3] = (short)bf16_rtn(a0.w);
        v[4] = (short)bf16_rtn(a1.x); v[5] = (short)bf16_rtn(a1.y);
        v[6] = (short)bf16_rtn(a1.z); v[7] = (short)bf16_rtn(a1.w);
        ((bf16x8*)Wf)[f] = v;
    }

    const int r0 = blockIdx.x * 128 + wave * 32;
    bf16x8 ahi[2][4], alo[2][4];
    #pragma unroll
    for (int rt = 0; rt < 2; ++rt) {
        int row = r0 + rt * 16 + l16;
        bool ok = (row < N);
        const float* xr = X + (size_t)(ok ? row : 0) * D;
        #pragma unroll
        for (int p = 0; p < 4; ++p) {
            int k0 = 32 * p + 8 * q;
            float4 a0 = ok ? *(const float4*)(xr + k0)     : make_float4(0, 0, 0, 0);
            float4 a1 = ok ? *(const float4*)(xr + k0 + 4) : make_float4(0, 0, 0, 0);
            float fv[8] = {a0.x, a0.y, a0.z, a0.w, a1.x, a1.y, a1.z, a1.w};
            bf16x8 h, l;
            #pragma unroll
            for (int e = 0; e < 8; ++e) {
                uint32_t u = __float_as_uint(fv[e]);
                h[e] = (short)(u >> 16);
                float hf = __uint_as_float(u & 0xFFFF0000u);
                l[e] = (short)(__float_as_uint(fv[e] - hf) >> 16);
            }
            ahi[rt][p] = h;
            alo[rt][p] = l;
        }
    }

    __syncthreads();

    f32x4 acc[2][8];
    #pragma unroll
    for (int rt = 0; rt < 2; ++rt)
        #pragma unroll
        for (int j = 0; j < 8; ++j) acc[rt][j] = (f32x4){0.f, 0.f, 0.f, 0.f};

    #pragma unroll
    for (int j = 0; j < 8; ++j) {
        #pragma unroll
        for (int p = 0; p < 4; ++p) {
            bf16x8 bb = ((bf16x8*)Wf)[(j * 4 + p) * 64 + lane];
            acc[0][j] = __builtin_amdgcn_mfma_f32_16x16x32_bf16(ahi[0][p], bb, acc[0][j], 0, 0, 0);
            acc[0][j] = __builtin_amdgcn_mfma_f32_16x16x32_bf16(alo[0][p], bb, acc[0][j], 0, 0, 0);
            acc[1][j] = __builtin_amdgcn_mfma_f32_16x16x32_bf16(ahi[1][p], bb, acc[1][j], 0, 0, 0);
            acc[1][j] = __builtin_amdgcn_mfma_f32_16x16x32_bf16(alo[1][p], bb, acc[1][j], 0, 0, 0);
        }
    }

    float bias[8];
    #pragma unroll
    for (int j = 0; j < 8; ++j) bias[j] = b[16 * j + l16];

    #pragma unroll
    for (int rt = 0; rt < 2; ++rt) {
        float ss[4] = {0.f, 0.f, 0.f, 0.f};
        #pragma unroll
        for (int j = 0; j < 8; ++j)
            #pragma unroll
            for (int r = 0; r < 4; ++r) {
                float v = acc[rt][j][r] + bias[j];
                acc[rt][j][r] = v;
                ss[r] += v * v;
            }
        #pragma unroll
        for (int m = 1; m <= 8; m <<= 1)
            #pragma unroll
            for (int r = 0; r < 4; ++r) ss[r] += __shfl_xor(ss[r], m);

        #pragma unroll
        for (int r = 0; r < 4; ++r) {
            int row = r0 + rt * 16 + 4 * q + r;
            if (row < N) {
                float f = NSCALE / fmaxf(sqrtf(ss[r]), NEPS) * post[row];
                #pragma unroll
                for (int j = 0; j < 8; ++j)
                    Abuf[(size_t)row * D + 16 * j + l16] = bf16_rtn(acc[rt][j][r] * f);
            }
        }
    }
}

// ---------------- CSR gather-aggregate (bf16 in, fp32 out) ----------------
// One wave per dst node: 4 groups of 16 lanes, each group gathers one row as
// ushort8 (16 B/lane). Unroll 4 -> 16 rows in flight per wave.
__global__ __launch_bounds__(256) void agg_kernel(const ushort* __restrict__ A,
                                                  const int* __restrict__ sorted_src,
                                                  const int* __restrict__ offs,
                                                  const int* __restrict__ cnt,
                                                  const float* __restrict__ norm_in,
                                                  float* __restrict__ out, int N) {
    int wave = threadIdx.x >> 6;
    int node = blockIdx.x * 4 + wave;
    if (node >= N) return;
    int lane = threadIdx.x & 63;
    int g = lane >> 4;          // edge group 0..3
    int c = lane & 15;          // column chunk: cols 8c..8c+7
    int beg = offs[node];
    int len = cnt[node];
    const ushort* Ac = A + c * 8;

    float acc[8] = {0.f, 0.f, 0.f, 0.f, 0.f, 0.f, 0.f, 0.f};
    int i = 0;
    for (; i + 16 <= len; i += 16) {
        int s0 = sorted_src[beg + i + g];
        int s1 = sorted_src[beg + i + 4 + g];
        int s2 = sorted_src[beg + i + 8 + g];
        int s3 = sorted_src[beg + i + 12 + g];
        u16x8 v0 = *(const u16x8*)(Ac + (size_t)s0 * D);
        u16x8 v1 = *(const u16x8*)(Ac + (size_t)s1 * D);
        u16x8 v2 = *(const u16x8*)(Ac + (size_t)s2 * D);
        u16x8 v3 = *(const u16x8*)(Ac + (size_t)s3 * D);
        #pragma unroll
        for (int e = 0; e < 8; ++e)
            acc[e] += (bf16_to_f(v0[e]) + bf16_to_f(v1[e])) +
                      (bf16_to_f(v2[e]) + bf16_to_f(v3[e]));
    }
    for (; i + 4 <= len; i += 4) {
        int s = sorted_src[beg + i + g];
        u16x8 v = *(const u16x8*)(Ac + (size_t)s * D);
        #pragma unroll
        for (int e = 0; e < 8; ++e) acc[e] += bf16_to_f(v[e]);
    }
    int rem = len - i;
    if (g < rem) {
        int s = sorted_src[beg + i + g];
        u16x8 v = *(const u16x8*)(Ac + (size_t)s * D);
        #pragma unroll
        for (int e = 0; e < 8; ++e) acc[e] += bf16_to_f(v[e]);
    }

    // reduce across the 4 groups (lanes differing in bits 4,5)
    #pragma unroll
    for (int e = 0; e < 8; ++e) {
        acc[e] += __shfl_xor(acc[e], 16);
        acc[e] += __shfl_xor(acc[e], 32);
    }

    if (g == 0) {
        float sc = norm_in[node];
        float4 w0 = make_float4(acc[0] * sc, acc[1] * sc, acc[2] * sc, acc[3] * sc);
        float4 w1 = make_float4(acc[4] * sc, acc[5] * sc, acc[6] * sc, acc[7] * sc);
        float* op = out + (size_t)node * D + c * 8;
        *(float4*)(op) = w0;
        *(float4*)(op + 4) = w1;
    }
}

// ---------------- launch ----------------

extern "C" void kernel_launch(void* const* d_in, const int* in_sizes, int n_in,
                              void* d_out, int out_size, void* d_ws, size_t ws_size,
                              hipStream_t stream) {
    const float* x  = (const float*)d_in[0];
    const float* W1 = (const float*)d_in[1];
    const float* b1 = (const float*)d_in[2];
    const float* W2 = (const float*)d_in[3];
    const float* b2 = (const float*)d_in[4];
    const int* src  = (const int*)d_in[5];
    const int* dst  = (const int*)d_in[6];
    float* out = (float*)d_out;

    const int N  = in_sizes[0] / D;        // 100000
    const int NE = in_sizes[5];            // 1600000
    const int NBK = (NE + EPB - 1) / EPB;  // 196  (must be <= 256)
    const int HB  = (N + NLO - 1) / NLO;   // 196  (must be <= 255)

    // workspace layout (256B aligned)
    char* w = (char*)d_ws;
    auto take = [&](size_t bytes) { char* p = w; w += (bytes + 255) & ~(size_t)255; return p; };
    int*    Hd       = (int*)take((size_t)NBK * 256 * 4);
    int*    Hs       = (int*)take((size_t)NBK * 256 * 4);
    int*    total_d  = (int*)take(256 * 4);
    int*    total_s  = (int*)take(256 * 4);
    int*    Bd       = (int*)take((size_t)(HB + 1) * 4);
    int*    Bs       = (int*)take((size_t)(HB + 1) * 4);
    int2*   sd_pair  = (int2*)take((size_t)NE * 8);
    int*    ss_src   = (int*)take((size_t)NE * 4);
    int*    ssrc     = (int*)take((size_t)NE * 4);
    int*    offs     = (int*)take((size_t)N * 4);
    int*    cnt_dst  = (int*)take((size_t)N * 4);
    float*  norm_in  = (float*)take((size_t)N * 4);
    float*  norm_out = (float*)take((size_t)N * 4);
    ushort* Abuf     = (ushort*)take((size_t)N * D * 2);

    // atomic-free MSB counting sort + degree norms
    hist_high_kernel<<<NBK, 256, 0, stream>>>(src, dst, Hd, Hs, NE);
    scan_cols_kernel<<<dim3(HB, 2), 256, 0, stream>>>(Hd, Hs, total_d, total_s, NBK);
    scan_tot_kernel<<<2, 256, 0, stream>>>(total_d, total_s, Bd, Bs, HB);
    scatter_high_kernel<<<NBK, 256, 0, stream>>>(src, dst, Hd, Hs, Bd, Bs,
                                                 sd_pair, ss_src, NE, HB);
    bucket_sort_kernel<<<HB, 512, 0, stream>>>(sd_pair, Bd, offs, cnt_dst,
                                               norm_in, ssrc, N);
    bucket_hist_kernel<<<HB, 512, 0, stream>>>(ss_src, Bs, norm_out, N);

    const int mlp_blocks = (N + 127) / 128;
    const int agg_blocks = (N + 3) / 4;    // one wave per node

    // layer 1: mlp(x) -> Abuf(bf16); agg -> h1 fp32 in d_out
    mlp_mfma_kernel<<<mlp_blocks, 256, 0, stream>>>(x, W1, b1, norm_out, Abuf, N);
    agg_kernel<<<agg_blocks, 256, 0, stream>>>(Abuf, ssrc, offs, cnt_dst, norm_in, out, N);

    // layer 2: mlp(h1) -> Abuf(bf16); agg -> final fp32 in d_out
    mlp_mfma_kernel<<<mlp_blocks, 256, 0, stream>>>(out, W2, b2, norm_out, Abuf, N);
    agg_kernel<<<agg_blocks, 256, 0, stream>>>(Abuf, ssrc, offs, cnt_dst, norm_in, out, N);
}